// Round 3
// baseline (152.647 us; speedup 1.0000x reference)
//
#include <hip/hip_runtime.h>

#define D_MODEL 1024
#define T_SEQ   512
#define B_BATCH 64
#define RPB     16   // consecutive rows (t) per emb block; 32 blocks per batch

// ---------------------------------------------------------------------------
// Phase 1: per-batch-row scan over T=512, one WAVE (64 lanes) per row.
// Each lane owns 8 consecutive t. Local serial scan + wave shuffle scan.
// No LDS, no barriers. (unchanged — ~4 us, not the bottleneck)
// ---------------------------------------------------------------------------
__global__ __launch_bounds__(64) void gpe_scan_kernel(
    const int* __restrict__ input_ids,
    const int* __restrict__ rel_ids,
    int* __restrict__ cp_role)
{
    const int b    = blockIdx.x;
    const int lane = threadIdx.x;            // 0..63
    const int base = b * T_SEQ + lane * 8;

    const int4 ra = *reinterpret_cast<const int4*>(rel_ids + base);
    const int4 rb = *reinterpret_cast<const int4*>(rel_ids + base + 4);
    const int4 ia = *reinterpret_cast<const int4*>(input_ids + base);
    const int4 ib = *reinterpret_cast<const int4*>(input_ids + base + 4);
    const int rel[8] = {ra.x, ra.y, ra.z, ra.w, rb.x, rb.y, rb.z, rb.w};
    const int id[8]  = {ia.x, ia.y, ia.z, ia.w, ib.x, ib.y, ib.z, ib.w};

    // local exclusive cumsum of inc
    int cl[8];
    int run = 0;
#pragma unroll
    for (int j = 0; j < 8; ++j) { cl[j] = run; run += (rel[j] > 0) ? 1 : 0; }

    // wave inclusive prefix sum of per-lane totals -> exclusive
    int incl = run;
#pragma unroll
    for (int off = 1; off < 64; off <<= 1) {
        const int n = __shfl_up(incl, off);
        if (lane >= off) incl += n;
    }
    const int excl = incl - run;

    int c[8];
#pragma unroll
    for (int j = 0; j < 8; ++j) c[j] = excl + cl[j];

    // prev_rel for j==0 comes from previous lane's rel[7]
    int prev0 = __shfl_up(rel[7], 1);
    if (lane == 0) prev0 = 0;

    // local inclusive cummax of (reset ? c : 0)
    int ml[8];
    int mrun = 0;
#pragma unroll
    for (int j = 0; j < 8; ++j) {
        const int prl  = (j == 0) ? prev0 : rel[j - 1];
        const int mask = (rel[j] == 0 && prl > 0) ? c[j] : 0;
        mrun = max(mrun, mask);
        ml[j] = mrun;
    }

    // wave inclusive prefix max of per-lane maxima -> exclusive
    int minc = mrun;
#pragma unroll
    for (int off = 1; off < 64; off <<= 1) {
        const int n = __shfl_up(minc, off);
        if (lane >= off) minc = max(minc, n);
    }
    int mexcl = __shfl_up(minc, 1);
    if (lane == 0) mexcl = 0;

    int outp[8];
#pragma unroll
    for (int j = 0; j < 8; ++j) {
        const int m    = max(mexcl, ml[j]);
        const int cp   = c[j] - m;
        const int role = (id[j] <= 4) ? 3 : ((rel[j] == 0) ? 2 : 0);
        outp[j] = cp | (role << 16);
    }
    *reinterpret_cast<int4*>(cp_role + base)     = make_int4(outp[0], outp[1], outp[2], outp[3]);
    *reinterpret_cast<int4*>(cp_role + base + 4) = make_int4(outp[4], outp[5], outp[6], outp[7]);
}

// ---------------------------------------------------------------------------
// Phase 2: out[b,t,d] = seq[t,d] + 0.5*chain[cp,d] + 0.3*depth[0,d]
//                       + 0.2*role_table[role,d]          (all f32)
//
// v4 change (SINGLE variable vs v3): blocking axis flipped back to
// (one batch, 16 CONSECUTIVE t). Each block now writes one CONTIGUOUS
// 64 KB span — the same access shape as the 6.7 TB/s harness fill —
// instead of 16 x 4 KB chunks at 2 MB stride. This is the previously
// unmeasured quadrant {no scratch bug, contiguous writes}: r0 had
// contiguous writes but the scratch bug; r1/r2 fixed scratch but
// scattered the writes. Cost: seq[t] is re-loaded per row (t varies
// within the block) from the L2-resident 2 MB table — ~4 us of L2
// reads, hidden under the write stream.
//
// Retained: scratch fix (role in {0,2,3} -> three NAMED float4 regs,
// ternary select, rule #20), plain (non-NT) float4 stores, block-uniform
// scalar cp_role loads.
// ---------------------------------------------------------------------------
__global__ __launch_bounds__(256) void gpe_emb_kernel(
    const float* __restrict__ seq_table,    // [512,1024]
    const float* __restrict__ chain_table,  // [1000,1024]
    const float* __restrict__ depth_table,  // [20,1024]
    const float* __restrict__ role_table,   // [4,1024]
    const int* __restrict__ cp_role,        // [B*T] packed cp|role<<16
    float* __restrict__ out)                // [B,T,1024]
{
    const int d0 = threadIdx.x << 2;                 // 0..1020, step 4
    const int b  = blockIdx.x >> 5;                  // 32 blocks per batch
    const int t0 = (blockIdx.x & 31) << 4;           // 16 consecutive rows
    const int rowbase = b * T_SEQ + t0;

    // Block-uniform packed cp|role for the block's 16 rows: consecutive
    // ints -> scalar s_load_dwordx4 merges, issued up-front.
    int pr[RPB];
#pragma unroll
    for (int k = 0; k < RPB; ++k)
        pr[k] = cp_role[rowbase + k];

    // base_r = 0.3*depth[0] + 0.2*role_table[r], r in {0,2,3}.
    // NAMED registers (no array!) so nothing can be demoted to scratch.
    const float4 dep = *reinterpret_cast<const float4*>(depth_table + d0);
    const float4 rv0 = *reinterpret_cast<const float4*>(role_table  + 0 * D_MODEL + d0);
    const float4 rv2 = *reinterpret_cast<const float4*>(role_table  + 2 * D_MODEL + d0);
    const float4 rv3 = *reinterpret_cast<const float4*>(role_table  + 3 * D_MODEL + d0);

    float4 b0v, b2v, b3v;
    b0v.x = 0.3f * dep.x + 0.2f * rv0.x;  b0v.y = 0.3f * dep.y + 0.2f * rv0.y;
    b0v.z = 0.3f * dep.z + 0.2f * rv0.z;  b0v.w = 0.3f * dep.w + 0.2f * rv0.w;
    b2v.x = 0.3f * dep.x + 0.2f * rv2.x;  b2v.y = 0.3f * dep.y + 0.2f * rv2.y;
    b2v.z = 0.3f * dep.z + 0.2f * rv2.z;  b2v.w = 0.3f * dep.w + 0.2f * rv2.w;
    b3v.x = 0.3f * dep.x + 0.2f * rv3.x;  b3v.y = 0.3f * dep.y + 0.2f * rv3.y;
    b3v.z = 0.3f * dep.z + 0.2f * rv3.z;  b3v.w = 0.3f * dep.w + 0.2f * rv3.w;

#pragma unroll
    for (int k = 0; k < RPB; ++k) {
        const int t    = t0 + k;
        const int cp   = pr[k] & 0xffff;
        const int role = pr[k] >> 16;

        const float4 sv = *reinterpret_cast<const float4*>(seq_table   + t  * D_MODEL + d0);
        const float4 cv = *reinterpret_cast<const float4*>(chain_table + cp * D_MODEL + d0);

        // role in {0,2,3}; uniform per row -> cndmask select, never memory.
        const float4 bv = (role == 3) ? b3v : ((role == 2) ? b2v : b0v);

        float4 ov;
        ov.x = (sv.x + bv.x) + 0.5f * cv.x;
        ov.y = (sv.y + bv.y) + 0.5f * cv.y;
        ov.z = (sv.z + bv.z) + 0.5f * cv.z;
        ov.w = (sv.w + bv.w) + 0.5f * cv.w;

        *reinterpret_cast<float4*>(out + (rowbase + k) * D_MODEL + d0) = ov;
    }
}

extern "C" void kernel_launch(void* const* d_in, const int* in_sizes, int n_in,
                              void* d_out, int out_size, void* d_ws, size_t ws_size,
                              hipStream_t stream) {
    const int* input_ids = (const int*)d_in[0];
    const int* rel_ids   = (const int*)d_in[1];
    const float* seq_table   = (const float*)d_in[2];
    const float* chain_table = (const float*)d_in[3];
    const float* depth_table = (const float*)d_in[4];
    const float* role_table  = (const float*)d_in[5];
    float* out = (float*)d_out;

    int* cp_role = (int*)d_ws;  // B*T ints = 128 KB

    gpe_scan_kernel<<<B_BATCH, 64, 0, stream>>>(input_ids, rel_ids, cp_role);

    const int n_blocks = B_BATCH * T_SEQ / RPB;  // 2048
    gpe_emb_kernel<<<n_blocks, 256, 0, stream>>>(
        seq_table, chain_table, depth_table, role_table, cp_role, out);
}

// Round 5
// 148.277 us; speedup vs baseline: 1.0295x; 1.0295x over previous
//
#include <hip/hip_runtime.h>

#define D_MODEL 1024
#define T_SEQ   512
#define B_BATCH 64
#define BGROUP  4    // batches per emb block; grid = (64/4) * 512 = 8192 blocks

// ---------------------------------------------------------------------------
// Phase 1: per-batch-row scan over T=512, one WAVE (64 lanes) per row.
// Each lane owns 8 consecutive t. Local serial scan + wave shuffle scan.
// No LDS, no barriers. (unchanged — ~4 us, not the bottleneck)
// ---------------------------------------------------------------------------
__global__ __launch_bounds__(64) void gpe_scan_kernel(
    const int* __restrict__ input_ids,
    const int* __restrict__ rel_ids,
    int* __restrict__ cp_role)
{
    const int b    = blockIdx.x;
    const int lane = threadIdx.x;            // 0..63
    const int base = b * T_SEQ + lane * 8;

    const int4 ra = *reinterpret_cast<const int4*>(rel_ids + base);
    const int4 rb = *reinterpret_cast<const int4*>(rel_ids + base + 4);
    const int4 ia = *reinterpret_cast<const int4*>(input_ids + base);
    const int4 ib = *reinterpret_cast<const int4*>(input_ids + base + 4);
    const int rel[8] = {ra.x, ra.y, ra.z, ra.w, rb.x, rb.y, rb.z, rb.w};
    const int id[8]  = {ia.x, ia.y, ia.z, ia.w, ib.x, ib.y, ib.z, ib.w};

    // local exclusive cumsum of inc
    int cl[8];
    int run = 0;
#pragma unroll
    for (int j = 0; j < 8; ++j) { cl[j] = run; run += (rel[j] > 0) ? 1 : 0; }

    // wave inclusive prefix sum of per-lane totals -> exclusive
    int incl = run;
#pragma unroll
    for (int off = 1; off < 64; off <<= 1) {
        const int n = __shfl_up(incl, off);
        if (lane >= off) incl += n;
    }
    const int excl = incl - run;

    int c[8];
#pragma unroll
    for (int j = 0; j < 8; ++j) c[j] = excl + cl[j];

    // prev_rel for j==0 comes from previous lane's rel[7]
    int prev0 = __shfl_up(rel[7], 1);
    if (lane == 0) prev0 = 0;

    // local inclusive cummax of (reset ? c : 0)
    int ml[8];
    int mrun = 0;
#pragma unroll
    for (int j = 0; j < 8; ++j) {
        const int prl  = (j == 0) ? prev0 : rel[j - 1];
        const int mask = (rel[j] == 0 && prl > 0) ? c[j] : 0;
        mrun = max(mrun, mask);
        ml[j] = mrun;
    }

    // wave inclusive prefix max of per-lane maxima -> exclusive
    int minc = mrun;
#pragma unroll
    for (int off = 1; off < 64; off <<= 1) {
        const int n = __shfl_up(minc, off);
        if (lane >= off) minc = max(minc, n);
    }
    int mexcl = __shfl_up(minc, 1);
    if (lane == 0) mexcl = 0;

    int outp[8];
#pragma unroll
    for (int j = 0; j < 8; ++j) {
        const int m    = max(mexcl, ml[j]);
        const int cp   = c[j] - m;
        const int role = (id[j] <= 4) ? 3 : ((rel[j] == 0) ? 2 : 0);
        outp[j] = cp | (role << 16);
    }
    *reinterpret_cast<int4*>(cp_role + base)     = make_int4(outp[0], outp[1], outp[2], outp[3]);
    *reinterpret_cast<int4*>(cp_role + base + 4) = make_int4(outp[4], outp[5], outp[6], outp[7]);
}

// ---------------------------------------------------------------------------
// Phase 2: out[b,t,d] = seq[t,d] + 0.5*chain[cp,d] + 0.3*depth[0,d]
//                       + 0.2*role_table[role,d]          (all f32)
//
// v5 change (SINGLE axis vs v3/v4): per-block tile 16 -> 4 rows, grid
// 2048 -> 8192 blocks, __launch_bounds__(256,4) (VGPR <= 128 floor).
// Theory H1: the 16-row fully-unrolled body (32 hoisted float4 loads +
// 16 stores live) either bloats VGPRs past the occupancy cliff or forces
// the scheduler into a serial load->wait->store chain per wave; either
// way per-CU memory-level parallelism collapses to a fraction of what
// the (8-VGPR, dependency-free) 6.6 TB/s fill sustains. Small tile +
// huge grid + reg cap = fill-shaped concurrency. The 4 chain loads are
// independent and issue up-front (~5 loads + 4 stores in flight/wave).
//
// Retained: same-t blocking (seq[t]+0.3*depth+0.2*role folded once into
// three NAMED base regs, rule #20 ternary select), plain float4 stores.
// ---------------------------------------------------------------------------
__global__ __launch_bounds__(256, 4) void gpe_emb_kernel(
    const float* __restrict__ seq_table,    // [512,1024]
    const float* __restrict__ chain_table,  // [1000,1024]
    const float* __restrict__ depth_table,  // [20,1024]
    const float* __restrict__ role_table,   // [4,1024]
    const int* __restrict__ cp_role,        // [B*T] packed cp|role<<16
    float* __restrict__ out)                // [B,T,1024]
{
    const int d0 = threadIdx.x << 2;                 // 0..1020, step 4
    const int t  = blockIdx.x & (T_SEQ - 1);         // one t per block
    const int b0 = (blockIdx.x >> 9) * BGROUP;       // batch group (0..15)*4

    // Block-uniform packed cp|role for the 4 rows (scalar loads, up-front).
    int pr[BGROUP];
#pragma unroll
    for (int k = 0; k < BGROUP; ++k)
        pr[k] = cp_role[(b0 + k) * T_SEQ + t];

    // Issue the 4 independent chain-row loads as early as possible.
    float4 cv0, cv1, cv2, cv3;
    {
        const int cp0 = pr[0] & 0xffff, cp1 = pr[1] & 0xffff;
        const int cp2 = pr[2] & 0xffff, cp3 = pr[3] & 0xffff;
        cv0 = *reinterpret_cast<const float4*>(chain_table + cp0 * D_MODEL + d0);
        cv1 = *reinterpret_cast<const float4*>(chain_table + cp1 * D_MODEL + d0);
        cv2 = *reinterpret_cast<const float4*>(chain_table + cp2 * D_MODEL + d0);
        cv3 = *reinterpret_cast<const float4*>(chain_table + cp3 * D_MODEL + d0);
    }

    // base_r = seq[t] + 0.3*depth[0] + 0.2*role_table[r], r in {0,2,3}.
    // NAMED registers (no array) so nothing can be demoted to scratch.
    const float4 sv  = *reinterpret_cast<const float4*>(seq_table   + t * D_MODEL + d0);
    const float4 dep = *reinterpret_cast<const float4*>(depth_table + d0);
    const float4 rv0 = *reinterpret_cast<const float4*>(role_table  + 0 * D_MODEL + d0);
    const float4 rv2 = *reinterpret_cast<const float4*>(role_table  + 2 * D_MODEL + d0);
    const float4 rv3 = *reinterpret_cast<const float4*>(role_table  + 3 * D_MODEL + d0);

    float4 sd;   // seq + 0.3*depth
    sd.x = sv.x + 0.3f * dep.x;
    sd.y = sv.y + 0.3f * dep.y;
    sd.z = sv.z + 0.3f * dep.z;
    sd.w = sv.w + 0.3f * dep.w;

    float4 b0v, b2v, b3v;
    b0v.x = sd.x + 0.2f * rv0.x;  b0v.y = sd.y + 0.2f * rv0.y;
    b0v.z = sd.z + 0.2f * rv0.z;  b0v.w = sd.w + 0.2f * rv0.w;
    b2v.x = sd.x + 0.2f * rv2.x;  b2v.y = sd.y + 0.2f * rv2.y;
    b2v.z = sd.z + 0.2f * rv2.z;  b2v.w = sd.w + 0.2f * rv2.w;
    b3v.x = sd.x + 0.2f * rv3.x;  b3v.y = sd.y + 0.2f * rv3.y;
    b3v.z = sd.z + 0.2f * rv3.z;  b3v.w = sd.w + 0.2f * rv3.w;

#pragma unroll
    for (int k = 0; k < BGROUP; ++k) {
        const int role = pr[k] >> 16;
        const float4 cv = (k == 0) ? cv0 : (k == 1) ? cv1 : (k == 2) ? cv2 : cv3;

        // role in {0,2,3}; uniform per row -> cndmask select, never memory.
        const float4 bv = (role == 3) ? b3v : ((role == 2) ? b2v : b0v);

        float4 ov;
        ov.x = bv.x + 0.5f * cv.x;
        ov.y = bv.y + 0.5f * cv.y;
        ov.z = bv.z + 0.5f * cv.z;
        ov.w = bv.w + 0.5f * cv.w;

        *reinterpret_cast<float4*>(out + ((b0 + k) * T_SEQ + t) * D_MODEL + d0) = ov;
    }
}

extern "C" void kernel_launch(void* const* d_in, const int* in_sizes, int n_in,
                              void* d_out, int out_size, void* d_ws, size_t ws_size,
                              hipStream_t stream) {
    const int* input_ids = (const int*)d_in[0];
    const int* rel_ids   = (const int*)d_in[1];
    const float* seq_table   = (const float*)d_in[2];
    const float* chain_table = (const float*)d_in[3];
    const float* depth_table = (const float*)d_in[4];
    const float* role_table  = (const float*)d_in[5];
    float* out = (float*)d_out;

    int* cp_role = (int*)d_ws;  // B*T ints = 128 KB

    gpe_scan_kernel<<<B_BATCH, 64, 0, stream>>>(input_ids, rel_ids, cp_role);

    const int n_blocks = (B_BATCH / BGROUP) * T_SEQ;  // 8192
    gpe_emb_kernel<<<n_blocks, 256, 0, stream>>>(
        seq_table, chain_table, depth_table, role_table, cp_role, out);
}